// Round 1
// baseline (167.785 us; speedup 1.0000x reference)
//
#include <hip/hip_runtime.h>

#define N_PIX   65536
#define N_GAUSS 2048

// Pack per-Gaussian data: g0 = {mu_x, mu_y, A, B}, g1 = {C, r, g, b}
// where quadratic form q = A*dx^2 + B*dx*dy + C*dy^2 already includes the
// -0.5*log2(e) factor so that w = exp2(q) == exp(-0.5 * maha).
__global__ __launch_bounds__(256) void prep_kernel(
        const float* __restrict__ mus,
        const float* __restrict__ covs,
        const float* __restrict__ cols,
        float4* __restrict__ gpack) {
    int m = blockIdx.x * blockDim.x + threadIdx.x;
    if (m >= N_GAUSS) return;
    float c00 = covs[4*m+0], c01 = covs[4*m+1];
    float c10 = covs[4*m+2], c11 = covs[4*m+3];
    float inv_det = 1.0f / (c00*c11 - c01*c10);
    const float k = -0.7213475204444817f;  // -0.5 * log2(e)
    float ia =  c11 * inv_det;             // cov_inv[0][0]
    float ib = -c01 * inv_det;             // cov_inv[0][1] == [1][0]
    float ic =  c00 * inv_det;             // cov_inv[1][1]
    float4 g0 = make_float4(mus[2*m+0], mus[2*m+1], k*ia, k*2.0f*ib);
    float4 g1 = make_float4(k*ic, cols[3*m+0], cols[3*m+1], cols[3*m+2]);
    gpack[2*m+0] = g0;
    gpack[2*m+1] = g1;
}

__global__ __launch_bounds__(256) void render_kernel(
        const float2* __restrict__ x,
        const float4* __restrict__ gpack,
        float* __restrict__ out) {
    int n = blockIdx.x * blockDim.x + threadIdx.x;
    float2 p = x[n];
    float accr = 0.f, accg = 0.f, accb = 0.f;
    #pragma unroll 8
    for (int m = 0; m < N_GAUSS; ++m) {
        float4 g0 = gpack[2*m+0];   // wave-uniform address -> broadcast
        float4 g1 = gpack[2*m+1];
        float dx = p.x - g0.x;
        float dy = p.y - g0.y;
        // q = A*dx^2 + B*dx*dy + C*dy^2  (A,B,C pre-scaled by -0.5*log2 e)
        float t  = fmaf(g0.z, dx, g0.w * dy);   // A*dx + B*dy
        float q  = fmaf(t, dx, g1.x * (dy*dy)); // t*dx + C*dy^2
        float w  = __builtin_amdgcn_exp2f(q);
        accr = fmaf(w, g1.y, accr);
        accg = fmaf(w, g1.z, accg);
        accb = fmaf(w, g1.w, accb);
    }
    out[3*n+0] = accr;
    out[3*n+1] = accg;
    out[3*n+2] = accb;
}

extern "C" void kernel_launch(void* const* d_in, const int* in_sizes, int n_in,
                              void* d_out, int out_size, void* d_ws, size_t ws_size,
                              hipStream_t stream) {
    const float* x    = (const float*)d_in[0];   // [N_PIX, 2]
    const float* mus  = (const float*)d_in[1];   // [N_GAUSS, 2]
    const float* covs = (const float*)d_in[2];   // [N_GAUSS, 2, 2]
    const float* cols = (const float*)d_in[3];   // [N_GAUSS, 3]
    float* out = (float*)d_out;                  // [N_PIX, 3]
    float4* gpack = (float4*)d_ws;               // 2048 * 32 B = 64 KB

    prep_kernel<<<(N_GAUSS + 255) / 256, 256, 0, stream>>>(mus, covs, cols, gpack);
    render_kernel<<<N_PIX / 256, 256, 0, stream>>>((const float2*)x, gpack, out);
}

// Round 2
// 101.278 us; speedup vs baseline: 1.6567x; 1.6567x over previous
//
#include <hip/hip_runtime.h>

#define N_PIX   65536
#define N_GAUSS 2048
#define GCHUNK  256                      // Gaussians per block
#define NCHUNK  (N_GAUSS / GCHUNK)       // 8 chunks
#define NPIXBLK (N_PIX / 256)            // 256 pixel blocks

// 8 blocks/CU (32 waves/CU) — second arg is min waves per SIMD.
__global__ __launch_bounds__(256, 8) void render_kernel(
        const float2* __restrict__ x,
        const float* __restrict__ mus,
        const float* __restrict__ covs,
        const float* __restrict__ cols,
        float* __restrict__ out) {
    // Packed per-Gaussian: lg[2m] = {mu_x, mu_y, A, B}, lg[2m+1] = {C, r, g, b}
    // with A,B,C pre-scaled by -0.5*log2(e) so w = exp2(quadform) = exp(-0.5*maha).
    __shared__ float4 lg[2 * GCHUNK];    // 8 KB

    int pixblk = blockIdx.x % NPIXBLK;
    int chunk  = blockIdx.x / NPIXBLK;
    int t = threadIdx.x;

    // Each thread inverts + packs one Gaussian of this block's chunk into LDS.
    {
        int m = chunk * GCHUNK + t;
        float c00 = covs[4*m+0], c01 = covs[4*m+1];
        float c10 = covs[4*m+2], c11 = covs[4*m+3];
        float inv_det = 1.0f / (c00*c11 - c01*c10);
        const float k = -0.7213475204444817f;   // -0.5 * log2(e)
        float ia =  c11 * inv_det;              // cov_inv[0][0]
        float ib = -c01 * inv_det;              // cov_inv[0][1] == [1][0]
        float ic =  c00 * inv_det;              // cov_inv[1][1]
        lg[2*t+0] = make_float4(mus[2*m+0], mus[2*m+1], k*ia, k*2.0f*ib);
        lg[2*t+1] = make_float4(k*ic, cols[3*m+0], cols[3*m+1], cols[3*m+2]);
    }
    __syncthreads();

    int n = pixblk * 256 + t;
    float2 p = x[n];
    float accr = 0.f, accg = 0.f, accb = 0.f;
    #pragma unroll 8
    for (int m = 0; m < GCHUNK; ++m) {
        float4 g0 = lg[2*m+0];   // uniform address -> LDS broadcast, no conflict
        float4 g1 = lg[2*m+1];
        float dx = p.x - g0.x;
        float dy = p.y - g0.y;
        float t1 = fmaf(g0.z, dx, g0.w * dy);      // A*dx + B*dy
        float q  = fmaf(t1, dx, g1.x * (dy*dy));   // + C*dy^2
        float w  = __builtin_amdgcn_exp2f(q);
        accr = fmaf(w, g1.y, accr);
        accg = fmaf(w, g1.z, accg);
        accb = fmaf(w, g1.w, accb);
    }
    // HW fp32 atomic add (global_atomic_add_f32); 8 chunks accumulate per pixel.
    unsafeAtomicAdd(&out[3*n+0], accr);
    unsafeAtomicAdd(&out[3*n+1], accg);
    unsafeAtomicAdd(&out[3*n+2], accb);
}

extern "C" void kernel_launch(void* const* d_in, const int* in_sizes, int n_in,
                              void* d_out, int out_size, void* d_ws, size_t ws_size,
                              hipStream_t stream) {
    const float* x    = (const float*)d_in[0];   // [N_PIX, 2]
    const float* mus  = (const float*)d_in[1];   // [N_GAUSS, 2]
    const float* covs = (const float*)d_in[2];   // [N_GAUSS, 2, 2]
    const float* cols = (const float*)d_in[3];   // [N_GAUSS, 3]
    float* out = (float*)d_out;                  // [N_PIX, 3]

    // d_out is re-poisoned to 0xAA before every launch — zero it (stream-ordered,
    // graph-capturable) since chunks accumulate atomically.
    hipMemsetAsync(out, 0, (size_t)out_size * sizeof(float), stream);

    render_kernel<<<NPIXBLK * NCHUNK, 256, 0, stream>>>(
        (const float2*)x, mus, covs, cols, out);
}